// Round 1
// baseline (1321.260 us; speedup 1.0000x reference)
//
#include <hip/hip_runtime.h>
#include <hip/hip_bf16.h>

typedef __bf16 bf16x8 __attribute__((ext_vector_type(8)));
typedef float f32x4 __attribute__((ext_vector_type(4)));

#define S_LEN 4096
#define EMB   512
#define NHEAD 8
#define HDIM  64
#define NBAT  2
#define NROW  (NBAT * S_LEN)   // 8192

static __device__ __forceinline__ f32x4 mfma16x16(bf16x8 a, bf16x8 b, f32x4 c) {
    return __builtin_amdgcn_mfma_f32_16x16x32_bf16(a, b, c, 0, 0, 0);
}

// ---------------- convert fp32 -> bf16 ----------------
__global__ __launch_bounds__(256) void convert_kernel(
    const float* __restrict__ x, const float* __restrict__ Wq,
    const float* __restrict__ Wk, const float* __restrict__ Wv,
    const float* __restrict__ Wo,
    __hip_bfloat16* __restrict__ xb, __hip_bfloat16* __restrict__ wqkv,
    __hip_bfloat16* __restrict__ wob)
{
    const int NX = NROW * EMB;     // 4194304
    const int NW = EMB * EMB;      // 262144 = 2^18
    int i = blockIdx.x * 256 + threadIdx.x;
    if (i < NX) { xb[i] = __float2bfloat16(x[i]); return; }
    int j = i - NX;
    if (j < 3 * NW) {
        int p = j >> 18, r = j & (NW - 1);
        const float* src = (p == 0) ? Wq : (p == 1) ? Wk : Wv;
        wqkv[j] = __float2bfloat16(src[r]);
    } else if (j < 4 * NW) {
        int r = j - 3 * NW;
        wob[r] = __float2bfloat16(Wo[r]);
    }
}

// ---------------- shared GEMM mainloop ----------------
// C[128x64] tile = A[128xK] * B[64xK]^T, A/B bf16 row-major along K (K=512).
// 4 waves; wave w -> rows w*32..w*32+31 (2 m-blocks), all 64 cols (4 n-blocks).
// LDS rows padded 32->40 elems (80B): 2-way max bank aliasing, 16B aligned.
__device__ __forceinline__ void gemm_core(
    const __hip_bfloat16* __restrict__ A, const __hip_bfloat16* __restrict__ Bw,
    int mbase, int nbase,
    __hip_bfloat16* As, __hip_bfloat16* Bs, f32x4 acc[2][4])
{
    const int tid = threadIdx.x;
    const int w = tid >> 6, lane = tid & 63, l = lane & 15, quad = lane >> 4;
    const f32x4 zero = {0.f, 0.f, 0.f, 0.f};
#pragma unroll
    for (int mb = 0; mb < 2; mb++)
#pragma unroll
        for (int nb = 0; nb < 4; nb++) acc[mb][nb] = zero;

    for (int k0 = 0; k0 < EMB; k0 += 32) {
        __syncthreads();
        // stage A: 128 rows x 32 cols bf16 = 512 chunks of 16B
#pragma unroll
        for (int c = tid; c < 512; c += 256) {
            int row = c >> 2, kc = c & 3;
            uint4 v = *(const uint4*)(A + (size_t)(mbase + row) * EMB + k0 + kc * 8);
            *(uint4*)(As + row * 40 + kc * 8) = v;
        }
        // stage B: 64 rows x 32 cols = 256 chunks
        {
            int row = tid >> 2, kc = tid & 3;
            uint4 v = *(const uint4*)(Bw + (size_t)(nbase + row) * EMB + k0 + kc * 8);
            *(uint4*)(Bs + row * 40 + kc * 8) = v;
        }
        __syncthreads();

        bf16x8 af[2], bfr[4];
#pragma unroll
        for (int mb = 0; mb < 2; mb++)
            af[mb] = *(const bf16x8*)(As + (w * 32 + mb * 16 + l) * 40 + quad * 8);
#pragma unroll
        for (int nb = 0; nb < 4; nb++)
            bfr[nb] = *(const bf16x8*)(Bs + (nb * 16 + l) * 40 + quad * 8);
#pragma unroll
        for (int mb = 0; mb < 2; mb++)
#pragma unroll
            for (int nb = 0; nb < 4; nb++)
                acc[mb][nb] = mfma16x16(af[mb], bfr[nb], acc[mb][nb]);
    }
}

// ---------------- QKV projection ----------------
// y = x @ W^T + b for W in {Wq,Wk,Wv} (concat rows 0..1535).
// Q,K stored [h][b][s][d]; V stored transposed [h][b][d][s].
__global__ __launch_bounds__(256, 4) void qkv_gemm(
    const __hip_bfloat16* __restrict__ xb, const __hip_bfloat16* __restrict__ wqkv,
    const float* __restrict__ bq, const float* __restrict__ bk, const float* __restrict__ bv,
    __hip_bfloat16* __restrict__ Qh, __hip_bfloat16* __restrict__ Kh,
    __hip_bfloat16* __restrict__ Vt)
{
    __shared__ __align__(16) __hip_bfloat16 As[128 * 40];
    __shared__ __align__(16) __hip_bfloat16 Bs[64 * 40];
    const int mbase = blockIdx.x * 128, nbase = blockIdx.y * 64;
    f32x4 acc[2][4];
    gemm_core(xb, wqkv, mbase, nbase, As, Bs, acc);

    const int tid = threadIdx.x;
    const int w = tid >> 6, lane = tid & 63, l = lane & 15, quad = lane >> 4;
    const int p = nbase >> 9;  // uniform per block: 0=Q,1=K,2=V
    const float* bias = (p == 0) ? bq : (p == 1) ? bk : bv;
    __hip_bfloat16* dst = (p == 0) ? Qh : (p == 1) ? Kh : Vt;
#pragma unroll
    for (int mb = 0; mb < 2; mb++)
#pragma unroll
        for (int nb = 0; nb < 4; nb++)
#pragma unroll
            for (int r = 0; r < 4; r++) {
                int m = mbase + w * 32 + mb * 16 + quad * 4 + r;
                int n = nbase + nb * 16 + l;
                int o = n & 511;
                float v = acc[mb][nb][r] + bias[o];
                int b = m >> 12, s = m & 4095, hh = o >> 6, d = o & 63;
                size_t idx = (p == 2)
                    ? ((size_t)((hh * 2 + b) * 64 + d)) * 4096 + s
                    : ((size_t)((hh * 2 + b) * 4096 + s)) * 64 + d;
                dst[idx] = __float2bfloat16(v);
            }
}

// ---------------- flash attention ----------------
// Block: (qt, h). 64 q-rows, BOTH batches (bias/mask tile loaded once, reused).
// Wave w owns q-rows w*16..w*16+15. Online softmax in exp2 domain.
__global__ __launch_bounds__(256, 2) void attn_kernel(
    const __hip_bfloat16* __restrict__ Qh, const __hip_bfloat16* __restrict__ Kh,
    const __hip_bfloat16* __restrict__ Vt,
    const float* __restrict__ bias, const int* __restrict__ mask,
    __hip_bfloat16* __restrict__ Om)
{
    const int h = blockIdx.y, qt = blockIdx.x;
    const int tid = threadIdx.x;
    const int w = tid >> 6, lane = tid & 63, l = lane & 15, quad = lane >> 4;
    const int q0 = qt * 64;
    const float CS = 0.18033688011112042f;  // (1/8) * log2(e)

    __shared__ __align__(16) __hip_bfloat16 Ks[2][64 * 72];
    __shared__ __align__(16) __hip_bfloat16 Vs[2][64 * 72];
    __shared__ __align__(16) __hip_bfloat16 Ps[64 * 72];

    // Q fragments (A-layout): row = q0 + w*16 + l, k = ks*32 + quad*8 + j
    bf16x8 qf[2][2];
#pragma unroll
    for (int b = 0; b < 2; b++) {
        const __hip_bfloat16* qp =
            Qh + ((size_t)((h * 2 + b) * 4096 + q0 + w * 16 + l)) * 64;
        qf[b][0] = *(const bf16x8*)(qp + quad * 8);
        qf[b][1] = *(const bf16x8*)(qp + 32 + quad * 8);
    }

    f32x4 oacc[2][4];
    float mst[2][4], lst[2][4];
    const f32x4 zero = {0.f, 0.f, 0.f, 0.f};
#pragma unroll
    for (int b = 0; b < 2; b++) {
#pragma unroll
        for (int nb = 0; nb < 4; nb++) oacc[b][nb] = zero;
#pragma unroll
        for (int r = 0; r < 4; r++) { mst[b][r] = -__builtin_inff(); lst[b][r] = 0.f; }
    }

    for (int kt = 0; kt < 64; kt++) {
        const int k0 = kt * 64;
        __syncthreads();  // protect Ks/Vs from prior-iter readers
        // stage K0,K1,V0,V1: 4 tiles x (64 rows x 8 chunks of 16B)
#pragma unroll
        for (int c = tid; c < 2048; c += 256) {
            int t = c >> 9;            // tile id (uniform within each strided iter)
            int b = t & 1, isV = t >> 1;
            int cc = c & 511, row = cc >> 3, ch = cc & 7;
            const __hip_bfloat16* src = isV
                ? Vt + ((size_t)((h * 2 + b) * 64 + row)) * 4096 + k0 + ch * 8
                : Kh + ((size_t)((h * 2 + b) * 4096 + k0 + row)) * 64 + ch * 8;
            uint4 v = *(const uint4*)src;
            *(uint4*)((isV ? Vs[b] : Ks[b]) + row * 72 + ch * 8) = v;
        }
        // bias/mask tile -> regs (shared by both batches); overlap with barrier
        float bor[4][4];
#pragma unroll
        for (int nb = 0; nb < 4; nb++)
#pragma unroll
            for (int r = 0; r < 4; r++) {
                int qq = q0 + w * 16 + quad * 4 + r;
                int kk = k0 + nb * 16 + l;
                float bb = bias[(size_t)h * S_LEN * S_LEN + (size_t)qq * S_LEN + kk];
                int mm = mask[(size_t)qq * S_LEN + kk];
                bor[nb][r] = mm ? bb : -1e30f;
            }
        __syncthreads();

#pragma unroll
        for (int b = 0; b < 2; b++) {
            // S = Q K^T
            f32x4 sc[4] = {zero, zero, zero, zero};
#pragma unroll
            for (int ks = 0; ks < 2; ks++)
#pragma unroll
                for (int nb = 0; nb < 4; nb++) {
                    bf16x8 kf = *(const bf16x8*)(Ks[b] + (nb * 16 + l) * 72 + ks * 32 + quad * 8);
                    sc[nb] = mfma16x16(qf[b][ks], kf, sc[nb]);
                }
            // masked-bias add, scale, online softmax (exp2 domain)
            float xv[4][4], rmax[4];
#pragma unroll
            for (int r = 0; r < 4; r++) rmax[r] = -__builtin_inff();
#pragma unroll
            for (int nb = 0; nb < 4; nb++)
#pragma unroll
                for (int r = 0; r < 4; r++) {
                    xv[nb][r] = (sc[nb][r] + bor[nb][r]) * CS;
                    rmax[r] = fmaxf(rmax[r], xv[nb][r]);
                }
#pragma unroll
            for (int r = 0; r < 4; r++) {
                rmax[r] = fmaxf(rmax[r], __shfl_xor(rmax[r], 1));
                rmax[r] = fmaxf(rmax[r], __shfl_xor(rmax[r], 2));
                rmax[r] = fmaxf(rmax[r], __shfl_xor(rmax[r], 4));
                rmax[r] = fmaxf(rmax[r], __shfl_xor(rmax[r], 8));
            }
            float alpha[4], rsum[4];
#pragma unroll
            for (int r = 0; r < 4; r++) {
                float mn = fmaxf(mst[b][r], rmax[r]);
                alpha[r] = __builtin_amdgcn_exp2f(mst[b][r] - mn);
                mst[b][r] = mn;
                rsum[r] = 0.f;
            }
            float pv[4][4];
#pragma unroll
            for (int nb = 0; nb < 4; nb++)
#pragma unroll
                for (int r = 0; r < 4; r++) {
                    float e = __builtin_amdgcn_exp2f(xv[nb][r] - mst[b][r]);
                    pv[nb][r] = e;
                    rsum[r] += e;
                }
#pragma unroll
            for (int r = 0; r < 4; r++) {
                rsum[r] += __shfl_xor(rsum[r], 1);
                rsum[r] += __shfl_xor(rsum[r], 2);
                rsum[r] += __shfl_xor(rsum[r], 4);
                rsum[r] += __shfl_xor(rsum[r], 8);
                lst[b][r] = lst[b][r] * alpha[r] + rsum[r];
            }
#pragma unroll
            for (int nb = 0; nb < 4; nb++)
#pragma unroll
                for (int r = 0; r < 4; r++) oacc[b][nb][r] *= alpha[r];
            // P -> LDS (each wave writes/reads ONLY its own 16 rows: no barrier)
#pragma unroll
            for (int nb = 0; nb < 4; nb++)
#pragma unroll
                for (int r = 0; r < 4; r++)
                    Ps[(w * 16 + quad * 4 + r) * 72 + nb * 16 + l] =
                        __float2bfloat16(pv[nb][r]);
            // O += P V
#pragma unroll
            for (int ks = 0; ks < 2; ks++) {
                bf16x8 pf = *(const bf16x8*)(Ps + (w * 16 + l) * 72 + ks * 32 + quad * 8);
#pragma unroll
                for (int nb = 0; nb < 4; nb++) {
                    bf16x8 vf = *(const bf16x8*)(Vs[b] + (nb * 16 + l) * 72 + ks * 32 + quad * 8);
                    oacc[b][nb] = mfma16x16(pf, vf, oacc[b][nb]);
                }
            }
        }
    }

    // epilogue: Om[b*4096+q][h*64+d] = O/l  (bf16, merged-head layout)
#pragma unroll
    for (int b = 0; b < 2; b++)
#pragma unroll
        for (int nb = 0; nb < 4; nb++)
#pragma unroll
            for (int r = 0; r < 4; r++) {
                int qq = q0 + w * 16 + quad * 4 + r;
                float val = oacc[b][nb][r] / lst[b][r];
                Om[((size_t)(b * 4096 + qq)) * 512 + h * 64 + nb * 16 + l] =
                    __float2bfloat16(val);
            }
}

// ---------------- output projection ----------------
__global__ __launch_bounds__(256, 4) void out_gemm(
    const __hip_bfloat16* __restrict__ Om, const __hip_bfloat16* __restrict__ wob,
    const float* __restrict__ bo, float* __restrict__ out)
{
    __shared__ __align__(16) __hip_bfloat16 As[128 * 40];
    __shared__ __align__(16) __hip_bfloat16 Bs[64 * 40];
    const int mbase = blockIdx.x * 128, nbase = blockIdx.y * 64;
    f32x4 acc[2][4];
    gemm_core(Om, wob, mbase, nbase, As, Bs, acc);

    const int tid = threadIdx.x;
    const int w = tid >> 6, lane = tid & 63, l = lane & 15, quad = lane >> 4;
#pragma unroll
    for (int mb = 0; mb < 2; mb++)
#pragma unroll
        for (int nb = 0; nb < 4; nb++)
#pragma unroll
            for (int r = 0; r < 4; r++) {
                int m = mbase + w * 32 + mb * 16 + quad * 4 + r;
                int n = nbase + nb * 16 + l;
                out[(size_t)m * EMB + n] = acc[mb][nb][r] + bo[n];
            }
}

extern "C" void kernel_launch(void* const* d_in, const int* in_sizes, int n_in,
                              void* d_out, int out_size, void* d_ws, size_t ws_size,
                              hipStream_t stream) {
    const float* x    = (const float*)d_in[0];
    const float* bias = (const float*)d_in[1];
    const int*   mask = (const int*)d_in[2];
    const float* Wq   = (const float*)d_in[3];
    const float* bq   = (const float*)d_in[4];
    const float* Wk   = (const float*)d_in[5];
    const float* bk   = (const float*)d_in[6];
    const float* Wv   = (const float*)d_in[7];
    const float* bv   = (const float*)d_in[8];
    const float* Wo   = (const float*)d_in[9];
    const float* bo   = (const float*)d_in[10];
    float* out = (float*)d_out;

    char* ws = (char*)d_ws;
    __hip_bfloat16* xb   = (__hip_bfloat16*)ws; ws += (size_t)NROW * EMB * 2;
    __hip_bfloat16* wqkv = (__hip_bfloat16*)ws; ws += (size_t)3 * EMB * EMB * 2;
    __hip_bfloat16* wob  = (__hip_bfloat16*)ws; ws += (size_t)EMB * EMB * 2;
    __hip_bfloat16* Qh   = (__hip_bfloat16*)ws; ws += (size_t)NROW * EMB * 2;
    __hip_bfloat16* Kh   = (__hip_bfloat16*)ws; ws += (size_t)NROW * EMB * 2;
    __hip_bfloat16* Vt   = (__hip_bfloat16*)ws; ws += (size_t)NROW * EMB * 2;
    __hip_bfloat16* Om   = (__hip_bfloat16*)ws; ws += (size_t)NROW * EMB * 2;

    // 1) fp32 -> bf16 conversions (exactly covers NX + 4*NW elements)
    convert_kernel<<<dim3(20480), dim3(256), 0, stream>>>(
        x, Wq, Wk, Wv, Wo, xb, wqkv, wob);
    // 2) fused QKV projection: M=8192, N=1536, K=512
    qkv_gemm<<<dim3(64, 24), dim3(256), 0, stream>>>(
        xb, wqkv, bq, bk, bv, Qh, Kh, Vt);
    // 3) flash attention, both batches per block
    attn_kernel<<<dim3(64, NHEAD), dim3(256), 0, stream>>>(
        Qh, Kh, Vt, bias, mask, Om);
    // 4) output projection: M=8192, N=512, K=512
    out_gemm<<<dim3(64, 8), dim3(256), 0, stream>>>(Om, wob, bo, out);
}